// Round 5
// baseline (643.470 us; speedup 1.0000x reference)
//
#include <hip/hip_runtime.h>
#include <hip/hip_bf16.h>

// NaryTreeLSTM  B=32768, K=4, I=256, H=256
// DTYPE MODEL (verified): inputs fp32, outputs fp32, bf16-scale threshold
// => bf16 MFMA pipeline, fp32 accum, fp32 out stores.
//
// ROUND-10: residency fix for BOTH kernels (both were ~21% occupancy,
//   latency-bound at 5x above HBM/MFMA floors).
// child: rewritten to root-R9 structure. Old design held 96 weight regs
//   (AGPR side of unified file, invisible in VGPR_Count=88) => combined
//   ~184 regs/wave => 2 waves/SIMD => ONE 8-wave block/CU (the 21%).
//   New: 512 thr, 64 rows x 128 cols/block, A in 32KB swizzled LDS (one
//   barrier), transient per-ks weight frags with 4x rt reuse. ~100 regs
//   => 2 blocks/CU = 16 waves. child_x re-read 2x -> L3-absorbed.
// root: 256->512 thr (8 waves share the same 64KB LDS), grid (512,2).
//   LDS cap was 2 blocks x 4 waves = 25%; now 2 x 8 = 50%. Per-wave code
//   identical to verified R9. launch_bounds(512,4) holds 128-reg cap.
//
// ws: cc [B][H][K] bf16, hsum [B][H] bf16, bf16 weight copies.

#define BB 32768
#define KK 4
#define II 256
#define HH 256

typedef __bf16 bf16x8 __attribute__((ext_vector_type(8)));
typedef __bf16 bf16x4 __attribute__((ext_vector_type(4)));
typedef float f32x4 __attribute__((ext_vector_type(4)));

#define MFMA16(a, b, c) __builtin_amdgcn_mfma_f32_16x16x32_bf16(a, b, c, 0, 0, 0)

static __device__ __forceinline__ float fsig(float x) {
    return 1.0f / (1.0f + __expf(-x));
}
static __device__ __forceinline__ float ftanhf(float x) {
    float e = __expf(2.0f * x);
    return 1.0f - 2.0f / (e + 1.0f);
}

// ---------------- Kernel 0: fp32 -> bf16 weight conversion ----------------
struct CvtArgs {
    const float* src[8];
    __bf16* dst[8];
    int n[8];
};
__global__ __launch_bounds__(256) void cvt_k(CvtArgs a) {
    const int t = blockIdx.y;
    const int i = (blockIdx.x * 256 + threadIdx.x) * 4;
    if (i < a.n[t]) {
        float4 f = *(const float4*)(a.src[t] + i);
        bf16x4 v;
        v[0] = (__bf16)f.x; v[1] = (__bf16)f.y; v[2] = (__bf16)f.z; v[3] = (__bf16)f.w;
        *(bf16x4*)(a.dst[t] + i) = v;
    }
}

// swizzled LDS fragment read: row stride 512B, byte ^= (row&7)<<4
#define LDA(plane, rt, ks) \
    (*(const bf16x8*)((const char*)(plane) + \
        ((((rt) * 16 + l16) * 512 + (cbase + (ks) * 32) * 2) ^ \
         ((((rt) * 16 + l16) & 7) << 4))))

// ---------------- Kernel 1: child gates, A-in-LDS ----------------
// Block: 512 thr = 8 waves; tile = 64 child-rows x 128 cols.
// grid.x = 4096: rowblock = bid>>1 (64 child rows), cg = bid&1 (col half).
// A staged once (fp32->bf16, swizzled), one barrier; per-ks transient
// weight frags (3 gates) reused across 4 row-tiles: 3 loads : 12 MFMAs.
__global__ __launch_bounds__(512, 4) void child_gates_k(
    const float* __restrict__ child_x,
    const __bf16* __restrict__ Wi, const __bf16* __restrict__ Wo,
    const __bf16* __restrict__ Wu,
    const float* __restrict__ bi, const float* __restrict__ bo,
    const float* __restrict__ bu,
    __bf16* __restrict__ cc, __bf16* __restrict__ hsum)
{
    const int tid  = threadIdx.x;
    const int lane = tid & 63;
    const int wave = tid >> 6;              // 0..7
    const int l16  = lane & 15;
    const int quad = lane >> 4;
    const int rowblock = blockIdx.x >> 1;   // 64 child rows each
    const int cg   = blockIdx.x & 1;        // column half
    const int crbase = rowblock * 64;
    const int ct   = cg * 8 + wave;
    const int n    = ct * 16 + l16;

    __shared__ __bf16 as_[64 * 256];

    // ---- stage child_x 64x256 fp32 -> bf16 swizzled LDS ----
    {
        const float* g = child_x + (size_t)crbase * II;
#pragma unroll
        for (int p = 0; p < 8; ++p) {
            const int e = p * 2048 + tid * 4;
            float4 f = *(const float4*)(g + e);
            bf16x4 v;
            v[0] = (__bf16)f.x; v[1] = (__bf16)f.y;
            v[2] = (__bf16)f.z; v[3] = (__bf16)f.w;
            const int r = e >> 8, c = e & 255;
            int off = r * 512 + c * 2;
            off ^= (r & 7) << 4;
            *(bf16x4*)((char*)as_ + off) = v;
        }
    }
    __syncthreads();    // only barrier; LDS read-only afterwards

    const float bin = bi[n], bon = bo[n], bun = bu[n];
    const int wo = n * II + quad * 8;
    const int cbase = quad * 8;

    f32x4 ai[4], ao[4], au[4];
    {
        const f32x4 z = {0.f, 0.f, 0.f, 0.f};
#pragma unroll
        for (int rt = 0; rt < 4; ++rt) { ai[rt] = z; ao[rt] = z; au[rt] = z; }
    }
#pragma unroll
    for (int ks = 0; ks < 8; ++ks) {
        const int o = wo + ks * 32;
        bf16x8 bwi = *(const bf16x8*)(Wi + o);
        bf16x8 bwo = *(const bf16x8*)(Wo + o);
        bf16x8 bwu = *(const bf16x8*)(Wu + o);
#pragma unroll
        for (int rt = 0; rt < 4; ++rt) {
            bf16x8 a = LDA(as_, rt, ks);
            ai[rt] = MFMA16(a, bwi, ai[rt]);
            ao[rt] = MFMA16(a, bwo, ao[rt]);
            au[rt] = MFMA16(a, bwu, au[rt]);
        }
    }

    // ---- epilogue: acc row = quad*4+r -> child row; k = r, b from quad ----
#pragma unroll
    for (int rt = 0; rt < 4; ++rt) {
        const int b = rowblock * 16 + rt * 4 + quad;
        float chs = 0.f;
        bf16x4 ccv4;
#pragma unroll
        for (int r = 0; r < 4; ++r) {
            float civ = fsig(ai[rt][r] + bin);
            float cov = fsig(ao[rt][r] + bon);
            float cuv = ftanhf(au[rt][r] + bun);
            float ccv = civ * cuv;
            chs += cov * ftanhf(ccv);
            ccv4[r] = (__bf16)ccv;
        }
        *(bf16x4*)(cc + ((size_t)b * HH + n) * KK) = ccv4;
        hsum[(size_t)b * HH + n] = (__bf16)chs;
    }
}

// ---------------- Kernel 2: root gates, A-in-LDS ----------------
// Block: 512 thr = 8 waves; block tile = 64 rows x 128 cols (wave ct =
// by*8+wave, 16 cols each). x+hsum staged once into swizzled LDS (one
// barrier), then each wave: pass1 (i,o,u; 6 wloads : 24 MFMA per ks),
// pass2 in rt-pair halves (5 wloads : 10 MFMA per ks).
__global__ __launch_bounds__(512, 4) void root_k(
    const float* __restrict__ x,
    const __bf16* __restrict__ Wi, const __bf16* __restrict__ Wf,
    const __bf16* __restrict__ Wo, const __bf16* __restrict__ Wu,
    const __bf16* __restrict__ Ui, const __bf16* __restrict__ Uo,
    const __bf16* __restrict__ Uu, const __bf16* __restrict__ WfK,
    const float* __restrict__ bi, const float* __restrict__ bf_,
    const float* __restrict__ bo, const float* __restrict__ bu,
    const __bf16* __restrict__ cc, const __bf16* __restrict__ hsum,
    float* __restrict__ out)
{
    const int tid  = threadIdx.x;
    const int lane = tid & 63;
    const int wave = tid >> 6;              // 0..7
    const int l16  = lane & 15;
    const int quad = lane >> 4;
    const int row0 = blockIdx.x * 64;       // block's 64 b-rows
    const int ct   = blockIdx.y * 8 + wave; // wave's 16 cols
    const int n    = ct * 16 + l16;

    __shared__ __bf16 xs[64 * 256];
    __shared__ __bf16 hsl[64 * 256];

    // ---- stage x (fp32 -> bf16) and hsum (bf16) ----
    {
        const float* xg = x + (size_t)row0 * II;
#pragma unroll
        for (int p = 0; p < 8; ++p) {
            const int e = p * 2048 + tid * 4;
            float4 f = *(const float4*)(xg + e);
            bf16x4 v;
            v[0] = (__bf16)f.x; v[1] = (__bf16)f.y;
            v[2] = (__bf16)f.z; v[3] = (__bf16)f.w;
            const int r = e >> 8, c = e & 255;
            int off = r * 512 + c * 2;
            off ^= (r & 7) << 4;
            *(bf16x4*)((char*)xs + off) = v;
        }
        const __bf16* hg = hsum + (size_t)row0 * HH;
#pragma unroll
        for (int p = 0; p < 4; ++p) {
            const int u = p * 512 + tid;    // 16B unit in 64x256
            bf16x8 v = *(const bf16x8*)(hg + u * 8);
            const int r = u >> 5, c = (u & 31) * 8;
            int off = r * 512 + c * 2;
            off ^= (r & 7) << 4;
            *(bf16x8*)((char*)hsl + off) = v;
        }
    }
    __syncthreads();    // the only barrier; LDS read-only afterwards

    const float bin = bi[n], bfn = bf_[n], bon = bo[n], bun = bu[n];
    const int wo = n * II + quad * 8;
    const int cbase = quad * 8;

    // ---- pass 1: i, o, u over 4 row-tiles ----
    f32x4 ai[4], ao[4], au[4];
    {
        const f32x4 z = {0.f, 0.f, 0.f, 0.f};
#pragma unroll
        for (int rt = 0; rt < 4; ++rt) { ai[rt] = z; ao[rt] = z; au[rt] = z; }
    }
#pragma unroll
    for (int ks = 0; ks < 8; ++ks) {
        const int o = wo + ks * 32;
        bf16x8 bwi = *(const bf16x8*)(Wi + o);
        bf16x8 bui = *(const bf16x8*)(Ui + o);
        bf16x8 bwo = *(const bf16x8*)(Wo + o);
        bf16x8 buo = *(const bf16x8*)(Uo + o);
        bf16x8 bwu = *(const bf16x8*)(Wu + o);
        bf16x8 buu = *(const bf16x8*)(Uu + o);
#pragma unroll
        for (int rt = 0; rt < 4; ++rt) {
            bf16x8 a = LDA(xs, rt, ks);
            bf16x8 h = LDA(hsl, rt, ks);
            ai[rt] = MFMA16(a, bwi, ai[rt]);
            ai[rt] = MFMA16(h, bui, ai[rt]);
            ao[rt] = MFMA16(a, bwo, ao[rt]);
            ao[rt] = MFMA16(h, buo, ao[rt]);
            au[rt] = MFMA16(a, bwu, au[rt]);
            au[rt] = MFMA16(h, buu, au[rt]);
        }
    }
    // nonlinearities; keep only i*u and o
    f32x4 cpart[4], ovv[4];
#pragma unroll
    for (int rt = 0; rt < 4; ++rt)
#pragma unroll
        for (int r = 0; r < 4; ++r) {
            const float iv = fsig(ai[rt][r] + bin);
            const float ov = fsig(ao[rt][r] + bon);
            const float uv = ftanhf(au[rt][r] + bun);
            cpart[rt][r] = iv * uv;
            ovv[rt][r]   = ov;
        }

    // ---- pass 2: f-family, two rt-pair halves ----
#pragma unroll
    for (int h2 = 0; h2 < 2; ++h2) {
        // prefetch cc gathers for this half's 32 rows
        bf16x4 cv4[2][4];
#pragma unroll
        for (int rt2 = 0; rt2 < 2; ++rt2)
#pragma unroll
            for (int r = 0; r < 4; ++r) {
                const int b = row0 + (h2 * 2 + rt2) * 16 + quad * 4 + r;
                cv4[rt2][r] = *(const bf16x4*)(cc + ((size_t)b * HH + n) * KK);
            }

        f32x4 axf[2], af0[2], af1[2], af2[2], af3[2];
        {
            const f32x4 z = {0.f, 0.f, 0.f, 0.f};
#pragma unroll
            for (int rt2 = 0; rt2 < 2; ++rt2) {
                axf[rt2] = z; af0[rt2] = z; af1[rt2] = z;
                af2[rt2] = z; af3[rt2] = z;
            }
        }
#pragma unroll
        for (int ks = 0; ks < 8; ++ks) {
            const int o = wo + ks * 32;
            bf16x8 bwf = *(const bf16x8*)(Wf + o);
            bf16x8 bk0 = *(const bf16x8*)(WfK + 0 * HH * II + o);
            bf16x8 bk1 = *(const bf16x8*)(WfK + 1 * HH * II + o);
            bf16x8 bk2 = *(const bf16x8*)(WfK + 2 * HH * II + o);
            bf16x8 bk3 = *(const bf16x8*)(WfK + 3 * HH * II + o);
#pragma unroll
            for (int rt2 = 0; rt2 < 2; ++rt2) {
                const int rt = h2 * 2 + rt2;
                bf16x8 a = LDA(xs, rt, ks);
                bf16x8 h = LDA(hsl, rt, ks);
                axf[rt2] = MFMA16(a, bwf, axf[rt2]);
                af0[rt2] = MFMA16(h, bk0, af0[rt2]);
                af1[rt2] = MFMA16(h, bk1, af1[rt2]);
                af2[rt2] = MFMA16(h, bk2, af2[rt2]);
                af3[rt2] = MFMA16(h, bk3, af3[rt2]);
            }
        }

        // epilogue for this half: fp32 stores
#pragma unroll
        for (int rt2 = 0; rt2 < 2; ++rt2) {
            const int rt = h2 * 2 + rt2;
#pragma unroll
            for (int r = 0; r < 4; ++r) {
                const int b = row0 + rt * 16 + quad * 4 + r;
                const float xfv = axf[rt2][r] + bfn;
                float cv = cpart[rt][r];
                cv += fsig(xfv + af0[rt2][r]) * (float)cv4[rt2][r][0];
                cv += fsig(xfv + af1[rt2][r]) * (float)cv4[rt2][r][1];
                cv += fsig(xfv + af2[rt2][r]) * (float)cv4[rt2][r][2];
                cv += fsig(xfv + af3[rt2][r]) * (float)cv4[rt2][r][3];
                const float hv = ovv[rt][r] * ftanhf(cv);
                out[(size_t)b * HH + n] = hv;                    // h
                out[(size_t)BB * HH + (size_t)b * HH + n] = cv;  // c
            }
        }
    }
}

extern "C" void kernel_launch(void* const* d_in, const int* in_sizes, int n_in,
                              void* d_out, int out_size, void* d_ws, size_t ws_size,
                              hipStream_t stream) {
    const float* x    = (const float*)d_in[0];
    const float* cx   = (const float*)d_in[1];
    const float* Wi   = (const float*)d_in[2];
    const float* bi   = (const float*)d_in[3];
    const float* Wf   = (const float*)d_in[4];
    const float* bf_  = (const float*)d_in[5];
    const float* Wo   = (const float*)d_in[6];
    const float* bo   = (const float*)d_in[7];
    const float* Wu   = (const float*)d_in[8];
    const float* bu   = (const float*)d_in[9];
    const float* Ui   = (const float*)d_in[10];
    const float* Uo   = (const float*)d_in[11];
    const float* Uu   = (const float*)d_in[12];
    const float* WfK  = (const float*)d_in[13];

    __bf16* cc = (__bf16*)d_ws;                     // [B][H][K]
    __bf16* hs = cc + (size_t)BB * KK * HH;         // [B][H]
    __bf16* wb = hs + (size_t)BB * HH;              // bf16 weight block
    __bf16 *Wi_b = wb,            *Wf_b = Wi_b + HH * II, *Wo_b = Wf_b + HH * II,
           *Wu_b = Wo_b + HH * II, *Ui_b = Wu_b + HH * II, *Uo_b = Ui_b + HH * HH,
           *Uu_b = Uo_b + HH * HH, *WfK_b = Uu_b + HH * HH;  // WfK: K*H*H

    CvtArgs ca;
    ca.src[0] = Wi;  ca.dst[0] = Wi_b;  ca.n[0] = HH * II;
    ca.src[1] = Wf;  ca.dst[1] = Wf_b;  ca.n[1] = HH * II;
    ca.src[2] = Wo;  ca.dst[2] = Wo_b;  ca.n[2] = HH * II;
    ca.src[3] = Wu;  ca.dst[3] = Wu_b;  ca.n[3] = HH * II;
    ca.src[4] = Ui;  ca.dst[4] = Ui_b;  ca.n[4] = HH * HH;
    ca.src[5] = Uo;  ca.dst[5] = Uo_b;  ca.n[5] = HH * HH;
    ca.src[6] = Uu;  ca.dst[6] = Uu_b;  ca.n[6] = HH * HH;
    ca.src[7] = WfK; ca.dst[7] = WfK_b; ca.n[7] = KK * HH * HH;

    cvt_k<<<dim3(KK * HH * HH / 1024, 8), dim3(256), 0, stream>>>(ca);
    child_gates_k<<<dim3(4096), dim3(512), 0, stream>>>(
        cx, Wi_b, Wo_b, Wu_b, bi, bo, bu, cc, hs);
    root_k<<<dim3(BB / 64, 2), dim3(512), 0, stream>>>(
        x, Wi_b, Wf_b, Wo_b, Wu_b, Ui_b, Uo_b, Uu_b, WfK_b,
        bi, bf_, bo, bu, cc, hs, (float*)d_out);
}